// Round 7
// baseline (1375.701 us; speedup 1.0000x reference)
//
#include <hip/hip_runtime.h>
#include <cstdint>
#include <cstddef>

#define NN   2048
#define BB   16
#define TT   12
#define FUT  12
#define HH   64
#define GG   256     // 4*H
#define KP   224     // K=198 padded to 7*32
#define ELLW 72
#define ASTR 232     // LDS A row stride in shorts (464 B, 16B-aligned)

typedef __attribute__((ext_vector_type(8))) short bf16x8;
typedef __attribute__((ext_vector_type(4))) float f32x4;

__device__ __forceinline__ float sigmoidf_(float x) {
    return 1.f / (1.f + __expf(-x));
}
__device__ __forceinline__ float tanhf_(float x) {
    const float e = __expf(2.f * x);
    return 1.f - 2.f / (e + 1.f);
}
__device__ __forceinline__ unsigned short f2bf(float x) {
    unsigned u = __builtin_bit_cast(unsigned, x);
    u += 0x7fffu + ((u >> 16) & 1u);
    return (unsigned short)(u >> 16);
}
__device__ __forceinline__ float bf2f(unsigned short s) {
    unsigned u = ((unsigned)s) << 16;
    return __builtin_bit_cast(float, u);
}

// ---------------------------------------------------------------------------
// ELL of L, deterministic ascending-column order, padded to multiple of 4
// (pad entries: col=n, val=0 -> exact no-op).
// ---------------------------------------------------------------------------
__global__ __launch_bounds__(256) void build_ell(
    const float* __restrict__ L, int* __restrict__ cols,
    float* __restrict__ vals, int* __restrict__ cnt)
{
    const int n = blockIdx.x;
    const int t = threadIdx.x;
    const float* row = L + (size_t)n * NN;
    float v[8];
    int c = 0;
#pragma unroll
    for (int i = 0; i < 8; ++i) {
        v[i] = row[t * 8 + i];
        c += (v[i] != 0.f);
    }
    __shared__ int s[256];
    s[t] = c;
    __syncthreads();
    for (int d = 1; d < 256; d <<= 1) {
        int add = (t >= d) ? s[t - d] : 0;
        __syncthreads();
        s[t] += add;
        __syncthreads();
    }
    int o = s[t] - c;
#pragma unroll
    for (int i = 0; i < 8; ++i) {
        if (v[i] != 0.f) {
            if (o < ELLW) {
                cols[n * ELLW + o] = t * 8 + i;
                vals[n * ELLW + o] = v[i];
            }
            ++o;
        }
    }
    if (t == 255) {
        int cn = (s[255] < ELLW) ? s[255] : ELLW;
        int cn4 = (cn + 3) & ~3;
        if (cn4 > ELLW) cn4 = ELLW;
        for (int p = cn; p < cn4; ++p) {
            cols[n * ELLW + p] = n;
            vals[n * ELLW + p] = 0.f;
        }
        cnt[n] = cn4;
    }
}

// ---------------------------------------------------------------------------
// W [198][256] fp32 -> W_t hi/lo [256][224] bf16 (transposed, K-padded).
// ---------------------------------------------------------------------------
__global__ __launch_bounds__(256) void wt_prep(
    const float* __restrict__ W, short* __restrict__ Wh, short* __restrict__ Wl)
{
    const int col = blockIdx.x;
    const int k = threadIdx.x;
    if (k < KP) {
        const float x = (k < 198) ? W[(size_t)k * GG + col] : 0.f;
        const unsigned short h = f2bf(x);
        const unsigned short l = f2bf(x - bf2f(h));
        Wh[(size_t)col * KP + k] = (short)h;
        Wl[(size_t)col * KP + k] = (short)l;
    }
}

// ---------------------------------------------------------------------------
// input [B][T][N][2] -> xt_all [T][N][B][2]  (node-major x, batch inner)
// ---------------------------------------------------------------------------
__global__ __launch_bounds__(256) void x_trans(
    const float* __restrict__ input, float* __restrict__ xt)
{
    const int o = blockIdx.x * 256 + threadIdx.x;   // 786432 total
    const int e = o & 1;
    const int b = (o >> 1) & 15;
    const int n = (o >> 5) & (NN - 1);
    const int t = o >> 16;
    xt[o] = input[(((size_t)b * TT + t) * NN + n) * 2 + e];
}

// ---------------------------------------------------------------------------
// t1h[n][b][0..63] (h-part, 256B rows) and t1x[n][b][0..1] (x-part, dense).
// One block per node, 4 waves = 4 h-quad-slices, lane = (b=lane>>2, j=lane&3).
// ---------------------------------------------------------------------------
__global__ __launch_bounds__(256) void spmm_t1(
    const float* __restrict__ xt,      // [N][16][2]
    const float* __restrict__ h,       // [N][16][64]
    const int* __restrict__ cols, const float* __restrict__ vals,
    const int* __restrict__ cnt,
    float* __restrict__ t1h, float* __restrict__ t1x)
{
    const int w = threadIdx.x >> 6, lane = threadIdx.x & 63;
    const int b = lane >> 2, j = lane & 3;
    const int n = blockIdx.x;
    const int cn = cnt[n];
    const int* cp = cols + n * ELLW;
    const float* vp = vals + n * ELLW;
    const int qoff = (4 * w + j) * 4;
    float a0 = 0.f, a1 = 0.f, a2 = 0.f, a3 = 0.f;
    float ax0 = 0.f, ax1 = 0.f;
#pragma unroll 4
    for (int jj = 0; jj < cn; ++jj) {
        const int m = cp[jj];
        const float v = vp[jj];
        const float4 g = *(const float4*)&h[((size_t)m * 16 + b) * HH + qoff];
        a0 += v * g.x; a1 += v * g.y; a2 += v * g.z; a3 += v * g.w;
        if (w == 0) {
            const float2 xg = *(const float2*)&xt[((size_t)m * 16 + b) * 2];
            ax0 += v * xg.x; ax1 += v * xg.y;
        }
    }
    *(float4*)&t1h[((size_t)n * 16 + b) * HH + qoff] = (float4){a0, a1, a2, a3};
    if (w == 0 && j == 0) {
        t1x[((size_t)n * 16 + b) * 2]     = ax0;
        t1x[((size_t)n * 16 + b) * 2 + 1] = ax1;
    }
}

// ---------------------------------------------------------------------------
// Fused cell step, node-major: block = 1 node x 16 batches = 16 A-rows,
// grid 2048 -> 8 blocks/CU (15 KB LDS, <=64 VGPR).
//   phase 1: waves = f-slices; stage comb/t1, gather t2, split bf16 hi/lo.
//   phase 2: MFMA GEMM; wave w owns gate-strided col-tiles {w,w+4,w+8,w+12}.
//   phase 3: LSTM elementwise; projection via LDS reduce.
// A k-cols: [0..65]=comb(x0,x1,h0..63)  [66..131]=t1  [132..197]=t2  [198..]=0
// ---------------------------------------------------------------------------
__global__ __launch_bounds__(256, 8) void cell_fused(
    const float* __restrict__ xt,      // [N][16][2]
    float* __restrict__ h, float* __restrict__ c,   // [N][16][64]
    const float* __restrict__ t1h,     // [N][16][64]
    const float* __restrict__ t1x,     // [N][16][2]
    const int* __restrict__ cols, const float* __restrict__ vals,
    const int* __restrict__ cnt,
    const short* __restrict__ Wh, const short* __restrict__ Wl,
    const float* __restrict__ bc,
    const float* __restrict__ W0, const float* __restrict__ b0,
    float* __restrict__ xout,          // [N][16][2]
    float* __restrict__ out, int jslot)
{
    __shared__ unsigned short Ah[16][ASTR];
    __shared__ unsigned short Al[16][ASTR];
    __shared__ float proj[4][16][2];
    const int tid = threadIdx.x, w = tid >> 6, lane = tid & 63;
    const int q = lane >> 4, c16 = lane & 15;
    const int b = lane >> 2, j = lane & 3;
    const int n = blockIdx.x;
    const int qoff = (4 * w + j) * 4;            // f-slice float offset (0..60)

    auto put = [&](int r, int k, float v) {
        const unsigned short hi = f2bf(v);
        Ah[r][k] = hi;
        Al[r][k] = f2bf(v - bf2f(hi));
    };

    // ---- zero pad cols 198..231
    {
        const int zr = tid >> 4, zs = tid & 15;
#pragma unroll
        for (int k0 = 198; k0 < 232; k0 += 16) {
            const int k = k0 + zs;
            if (k < 232) { Ah[zr][k] = 0; Al[zr][k] = 0; }
        }
    }

    // ---- phase 1: stage + gather (row r = b)
    {
        const size_t rb = (size_t)n * 16 + b;
        const float4 hq = *(const float4*)&h[rb * HH + qoff];
        const float4 tq = *(const float4*)&t1h[rb * HH + qoff];
        float xo0 = 0.f, xo1 = 0.f, t160 = 0.f, t161 = 0.f;
        if (w == 1) {
            const float2 xv = *(const float2*)&xt[rb * 2];
            xo0 = xv.x; xo1 = xv.y;
            const float2 tv = *(const float2*)&t1x[rb * 2];
            t160 = tv.x; t161 = tv.y;
        }
        const int cn = cnt[n];
        const int* cp = cols + n * ELLW;
        const float* vp = vals + n * ELLW;
        float a0 = 0.f, a1 = 0.f, a2 = 0.f, a3 = 0.f, ax0 = 0.f, ax1 = 0.f;
#pragma unroll 4
        for (int jj = 0; jj < cn; ++jj) {
            const int m = cp[jj];
            const float v = vp[jj];
            const size_t mb = (size_t)m * 16 + b;
            const float4 g = *(const float4*)&t1h[mb * HH + qoff];
            a0 += v * g.x; a1 += v * g.y; a2 += v * g.z; a3 += v * g.w;
            if (w == 1) {
                const float2 gx = *(const float2*)&t1x[mb * 2];
                ax0 += v * gx.x; ax1 += v * gx.y;
            }
        }
        const int r = b;
        put(r, 2 + qoff + 0, hq.x);  put(r, 2 + qoff + 1, hq.y);
        put(r, 2 + qoff + 2, hq.z);  put(r, 2 + qoff + 3, hq.w);
        put(r, 68 + qoff + 0, tq.x); put(r, 68 + qoff + 1, tq.y);
        put(r, 68 + qoff + 2, tq.z); put(r, 68 + qoff + 3, tq.w);
        put(r, 134 + qoff + 0, 2.f * a0 - hq.x);
        put(r, 134 + qoff + 1, 2.f * a1 - hq.y);
        put(r, 134 + qoff + 2, 2.f * a2 - hq.z);
        put(r, 134 + qoff + 3, 2.f * a3 - hq.w);
        if (w == 1 && j == 0) {
            put(r, 0, xo0);   put(r, 1, xo1);
            put(r, 66, t160); put(r, 67, t161);
            put(r, 132, 2.f * ax0 - xo0);
            put(r, 133, 2.f * ax1 - xo1);
        }
    }
    __syncthreads();

    // ---- phase 2: MFMA GEMM (1 row-tile x 4 gate-tiles, B in 2 groups)
    f32x4 acc[4];
#pragma unroll
    for (int g = 0; g < 4; ++g) acc[g] = (f32x4){0.f, 0.f, 0.f, 0.f};

#pragma unroll 1
    for (int kc = 0; kc < 7; ++kc) {
        const int ko = kc * 32 + q * 8;
        const bf16x8 ah = *(const bf16x8*)&Ah[c16][ko];
        const bf16x8 al = *(const bf16x8*)&Al[c16][ko];
#pragma unroll
        for (int gp = 0; gp < 4; gp += 2) {
            const int col0 = (w + 4 * gp) * 16 + c16;
            const int col1 = (w + 4 * (gp + 1)) * 16 + c16;
            const bf16x8 bh0 = *(const bf16x8*)(Wh + (size_t)col0 * KP + ko);
            const bf16x8 bl0 = *(const bf16x8*)(Wl + (size_t)col0 * KP + ko);
            const bf16x8 bh1 = *(const bf16x8*)(Wh + (size_t)col1 * KP + ko);
            const bf16x8 bl1 = *(const bf16x8*)(Wl + (size_t)col1 * KP + ko);
            acc[gp] = __builtin_amdgcn_mfma_f32_16x16x32_bf16(ah, bh0, acc[gp], 0, 0, 0);
            acc[gp] = __builtin_amdgcn_mfma_f32_16x16x32_bf16(al, bh0, acc[gp], 0, 0, 0);
            acc[gp] = __builtin_amdgcn_mfma_f32_16x16x32_bf16(ah, bl0, acc[gp], 0, 0, 0);
            acc[gp + 1] = __builtin_amdgcn_mfma_f32_16x16x32_bf16(ah, bh1, acc[gp + 1], 0, 0, 0);
            acc[gp + 1] = __builtin_amdgcn_mfma_f32_16x16x32_bf16(al, bh1, acc[gp + 1], 0, 0, 0);
            acc[gp + 1] = __builtin_amdgcn_mfma_f32_16x16x32_bf16(ah, bl1, acc[gp + 1], 0, 0, 0);
        }
    }

    // ---- phase 3: LSTM elementwise (unit u = 16*w + c16 lane-local)
    const int u = 16 * w + c16;
    const float bi = bc[u], bfv = bc[64 + u], bo = bc[128 + u], bg = bc[192 + u];
    float h2v[4];
#pragma unroll
    for (int reg = 0; reg < 4; ++reg) {
        const int bb = q * 4 + reg;
        const size_t idx = ((size_t)n * 16 + bb) * HH + u;
        const float ig = sigmoidf_(acc[0][reg] + bi);
        const float fg = sigmoidf_(acc[1][reg] + bfv);
        const float og = sigmoidf_(acc[2][reg] + bo);
        const float gg = tanhf_(acc[3][reg] + bg);
        const float c2 = fg * c[idx] + ig * gg;
        const float h2 = og * tanhf_(c2);
        c[idx] = c2;
        h[idx] = h2;
        h2v[reg] = h2;
    }

    if (jslot >= 0) {
        const float w0u = W0[u * 2], w1u = W0[u * 2 + 1];
#pragma unroll
        for (int reg = 0; reg < 4; ++reg) {
            float s0 = h2v[reg] * w0u;
            float s1 = h2v[reg] * w1u;
#pragma unroll
            for (int d = 1; d <= 8; d <<= 1) {
                s0 += __shfl_xor(s0, d, 64);
                s1 += __shfl_xor(s1, d, 64);
            }
            if (c16 == 0) {
                const int lr = q * 4 + reg;
                proj[w][lr][0] = s0;
                proj[w][lr][1] = s1;
            }
        }
        __syncthreads();
        if (tid < 32) {
            const int lr = tid >> 1, comp = tid & 1;
            const float v = proj[0][lr][comp] + proj[1][lr][comp] +
                            proj[2][lr][comp] + proj[3][lr][comp] + b0[comp];
            const float y = tanhf_(v);
            xout[((size_t)n * 16 + lr) * 2 + comp] = y;
            out[(((size_t)lr * FUT + jslot) * NN + n) * 2 + comp] = y;
        }
    }
}

// ---------------------------------------------------------------------------
extern "C" void kernel_launch(void* const* d_in, const int* in_sizes, int n_in,
                              void* d_out, int out_size, void* d_ws, size_t ws_size,
                              hipStream_t stream)
{
    const float* input = (const float*)d_in[0];   // [B,T,N,2]
    const float* L     = (const float*)d_in[1];   // [N,N]
    const float* W     = (const float*)d_in[2];   // [198,256]
    const float* bc    = (const float*)d_in[3];   // [256]
    const float* W0    = (const float*)d_in[4];   // [64,2]
    const float* b0    = (const float*)d_in[5];   // [2]

    char* ws = (char*)d_ws;
    size_t off = 0;
    auto carve = [&](size_t bytes) {
        void* p = ws + off;
        off += (bytes + 255) & ~(size_t)255;
        return p;
    };
    int*   cols  = (int*)  carve((size_t)NN * ELLW * 4);
    float* vals  = (float*)carve((size_t)NN * ELLW * 4);
    int*   cnt   = (int*)  carve((size_t)NN * 4);
    float* t1h   = (float*)carve((size_t)NN * 16 * HH * 4);
    float* t1x   = (float*)carve((size_t)NN * 16 * 2 * 4);
    float* h     = (float*)carve((size_t)NN * 16 * HH * 4);
    float* c     = (float*)carve((size_t)NN * 16 * HH * 4);
    float* xbuf  = (float*)carve((size_t)NN * 16 * 2 * 4);
    float* xtall = (float*)carve((size_t)TT * NN * 16 * 2 * 4);
    short* Wh    = (short*)carve((size_t)GG * KP * 2);
    short* Wl    = (short*)carve((size_t)GG * KP * 2);
    float* out   = (float*)d_out;

    build_ell<<<NN, 256, 0, stream>>>(L, cols, vals, cnt);
    wt_prep<<<GG, 256, 0, stream>>>(W, Wh, Wl);
    x_trans<<<(TT * NN * 16 * 2) / 256, 256, 0, stream>>>(input, xtall);
    hipMemsetAsync(h, 0, (size_t)NN * 16 * HH * 4, stream);
    hipMemsetAsync(c, 0, (size_t)NN * 16 * HH * 4, stream);

    for (int t = 0; t < TT; ++t) {
        const float* xt = xtall + (size_t)t * NN * 16 * 2;
        spmm_t1<<<NN, 256, 0, stream>>>(xt, h, cols, vals, cnt, t1h, t1x);
        cell_fused<<<NN, 256, 0, stream>>>(xt, h, c, t1h, t1x, cols, vals, cnt,
                                           Wh, Wl, bc, W0, b0, xbuf, out,
                                           (t == TT - 1) ? 0 : -1);
    }
    for (int jstep = 1; jstep < FUT; ++jstep) {
        spmm_t1<<<NN, 256, 0, stream>>>(xbuf, h, cols, vals, cnt, t1h, t1x);
        cell_fused<<<NN, 256, 0, stream>>>(xbuf, h, c, t1h, t1x, cols, vals, cnt,
                                           Wh, Wl, bc, W0, b0, xbuf, out, jstep);
    }
}

// Round 8
// 1175.684 us; speedup vs baseline: 1.1701x; 1.1701x over previous
//
#include <hip/hip_runtime.h>
#include <cstdint>
#include <cstddef>

#define NN   2048
#define BB   16
#define TT   12
#define FUT  12
#define HH   64
#define GG   256     // 4*H
#define KP   224     // K=198 padded to 7*32
#define ELLW 72
#define ASTR 232     // LDS A row stride in shorts (464 B, 16B-aligned)

typedef __attribute__((ext_vector_type(8))) short bf16x8;
typedef __attribute__((ext_vector_type(4))) float f32x4;

__device__ __forceinline__ float sigmoidf_(float x) {
    return 1.f / (1.f + __expf(-x));
}
__device__ __forceinline__ float tanhf_(float x) {
    const float e = __expf(2.f * x);
    return 1.f - 2.f / (e + 1.f);
}
__device__ __forceinline__ unsigned short f2bf(float x) {
    unsigned u = __builtin_bit_cast(unsigned, x);
    u += 0x7fffu + ((u >> 16) & 1u);
    return (unsigned short)(u >> 16);
}
__device__ __forceinline__ float bf2f(unsigned short s) {
    unsigned u = ((unsigned)s) << 16;
    return __builtin_bit_cast(float, u);
}

// ---------------------------------------------------------------------------
// ELL of L, deterministic ascending-column order, padded to multiple of 4
// (pad entries: col=n, val=0 -> exact no-op).
// ---------------------------------------------------------------------------
__global__ __launch_bounds__(256) void build_ell(
    const float* __restrict__ L, int* __restrict__ cols,
    float* __restrict__ vals, int* __restrict__ cnt)
{
    const int n = blockIdx.x;
    const int t = threadIdx.x;
    const float* row = L + (size_t)n * NN;
    float v[8];
    int c = 0;
#pragma unroll
    for (int i = 0; i < 8; ++i) {
        v[i] = row[t * 8 + i];
        c += (v[i] != 0.f);
    }
    __shared__ int s[256];
    s[t] = c;
    __syncthreads();
    for (int d = 1; d < 256; d <<= 1) {
        int add = (t >= d) ? s[t - d] : 0;
        __syncthreads();
        s[t] += add;
        __syncthreads();
    }
    int o = s[t] - c;
#pragma unroll
    for (int i = 0; i < 8; ++i) {
        if (v[i] != 0.f) {
            if (o < ELLW) {
                cols[n * ELLW + o] = t * 8 + i;
                vals[n * ELLW + o] = v[i];
            }
            ++o;
        }
    }
    if (t == 255) {
        int cn = (s[255] < ELLW) ? s[255] : ELLW;
        int cn4 = (cn + 3) & ~3;
        if (cn4 > ELLW) cn4 = ELLW;
        for (int p = cn; p < cn4; ++p) {
            cols[n * ELLW + p] = n;
            vals[n * ELLW + p] = 0.f;
        }
        cnt[n] = cn4;
    }
}

// ---------------------------------------------------------------------------
// W [198][256] fp32 -> W_t hi/lo [256][224] bf16 (transposed, K-padded).
// ---------------------------------------------------------------------------
__global__ __launch_bounds__(256) void wt_prep(
    const float* __restrict__ W, short* __restrict__ Wh, short* __restrict__ Wl)
{
    const int col = blockIdx.x;
    const int k = threadIdx.x;
    if (k < KP) {
        const float x = (k < 198) ? W[(size_t)k * GG + col] : 0.f;
        const unsigned short h = f2bf(x);
        const unsigned short l = f2bf(x - bf2f(h));
        Wh[(size_t)col * KP + k] = (short)h;
        Wl[(size_t)col * KP + k] = (short)l;
    }
}

// ---------------------------------------------------------------------------
// input [B][T][N][2] -> xt_all [T][N][B][2]  (node-major x, batch inner)
// ---------------------------------------------------------------------------
__global__ __launch_bounds__(256) void x_trans(
    const float* __restrict__ input, float* __restrict__ xt)
{
    const int o = blockIdx.x * 256 + threadIdx.x;   // 786432 total
    const int e = o & 1;
    const int b = (o >> 1) & 15;
    const int n = (o >> 5) & (NN - 1);
    const int t = o >> 16;
    xt[o] = input[(((size_t)b * TT + t) * NN + n) * 2 + e];
}

// ---------------------------------------------------------------------------
// t1h[n][b][0..63] (h-part, 256B rows) and t1x[n][b][0..1] (x-part, dense).
// One block per node, 4 waves = 4 h-quad-slices, lane = (b=lane>>2, j=lane&3).
// ---------------------------------------------------------------------------
__global__ __launch_bounds__(256) void spmm_t1(
    const float* __restrict__ xt,      // [N][16][2]
    const float* __restrict__ h,       // [N][16][64]
    const int* __restrict__ cols, const float* __restrict__ vals,
    const int* __restrict__ cnt,
    float* __restrict__ t1h, float* __restrict__ t1x)
{
    const int w = threadIdx.x >> 6, lane = threadIdx.x & 63;
    const int b = lane >> 2, j = lane & 3;
    const int n = blockIdx.x;
    const int cn = cnt[n];
    const int* cp = cols + n * ELLW;
    const float* vp = vals + n * ELLW;
    const int qoff = (4 * w + j) * 4;
    float a0 = 0.f, a1 = 0.f, a2 = 0.f, a3 = 0.f;
    float ax0 = 0.f, ax1 = 0.f;
#pragma unroll 4
    for (int jj = 0; jj < cn; ++jj) {
        const int m = cp[jj];
        const float v = vp[jj];
        const float4 g = *(const float4*)&h[((size_t)m * 16 + b) * HH + qoff];
        a0 += v * g.x; a1 += v * g.y; a2 += v * g.z; a3 += v * g.w;
        if (w == 0) {
            const float2 xg = *(const float2*)&xt[((size_t)m * 16 + b) * 2];
            ax0 += v * xg.x; ax1 += v * xg.y;
        }
    }
    *(float4*)&t1h[((size_t)n * 16 + b) * HH + qoff] = (float4){a0, a1, a2, a3};
    if (w == 0 && j == 0) {
        t1x[((size_t)n * 16 + b) * 2]     = ax0;
        t1x[((size_t)n * 16 + b) * 2 + 1] = ax1;
    }
}

// ---------------------------------------------------------------------------
// Fused cell step, node-major: block = 2 nodes x 16 batches = 32 A-rows,
// grid 1024 -> 4 blocks/CU (30.7 KB LDS, VGPR budget relaxed to 4 waves/SIMD).
//   phase 1: waves = f-slices; stage comb/t1, gather t2 (256B coalesced rows),
//            split to bf16 hi/lo LDS tiles.
//   phase 2: MFMA GEMM; wave w owns gate-strided col-tiles {w,w+4,w+8,w+12}.
//   phase 3: LSTM elementwise; projection via LDS reduce.
// A k-cols: [0..65]=comb(x0,x1,h0..63)  [66..131]=t1  [132..197]=t2  [198..]=0
// ---------------------------------------------------------------------------
__global__ __launch_bounds__(256, 4) void cell_fused(
    const float* __restrict__ xt,      // [N][16][2]
    float* __restrict__ h, float* __restrict__ c,   // [N][16][64]
    const float* __restrict__ t1h,     // [N][16][64]
    const float* __restrict__ t1x,     // [N][16][2]
    const int* __restrict__ cols, const float* __restrict__ vals,
    const int* __restrict__ cnt,
    const short* __restrict__ Wh, const short* __restrict__ Wl,
    const float* __restrict__ bc,
    const float* __restrict__ W0, const float* __restrict__ b0,
    float* __restrict__ xout,          // [N][16][2]
    float* __restrict__ out, int jslot)
{
    __shared__ unsigned short Ah[32][ASTR];
    __shared__ unsigned short Al[32][ASTR];
    __shared__ float proj[4][32][2];
    const int tid = threadIdx.x, w = tid >> 6, lane = tid & 63;
    const int q = lane >> 4, c16 = lane & 15;
    const int b = lane >> 2, j = lane & 3;
    const int n0 = blockIdx.x * 2;
    const int qoff = (4 * w + j) * 4;            // f-slice float offset (0..60)

    auto put = [&](int r, int k, float v) {
        const unsigned short hi = f2bf(v);
        Ah[r][k] = hi;
        Al[r][k] = f2bf(v - bf2f(hi));
    };

    // ---- zero pad cols 198..231
    {
        const int zr = tid >> 3, zs = tid & 7;
#pragma unroll
        for (int k0 = 198; k0 < 232; k0 += 8) {
            const int k = k0 + zs;
            if (k < 232) { Ah[zr][k] = 0; Al[zr][k] = 0; }
        }
    }

    // ---- phase 1: per node, stage + gather
#pragma unroll
    for (int ln = 0; ln < 2; ++ln) {
        const int n = n0 + ln;
        const size_t rb = (size_t)n * 16 + b;
        const int r = ln * 16 + b;
        const float4 hq = *(const float4*)&h[rb * HH + qoff];
        const float4 tq = *(const float4*)&t1h[rb * HH + qoff];
        float xo0 = 0.f, xo1 = 0.f, t160 = 0.f, t161 = 0.f;
        if (w == 1) {
            const float2 xv = *(const float2*)&xt[rb * 2];
            xo0 = xv.x; xo1 = xv.y;
            const float2 tv = *(const float2*)&t1x[rb * 2];
            t160 = tv.x; t161 = tv.y;
        }
        const int cn = cnt[n];
        const int* cp = cols + n * ELLW;
        const float* vp = vals + n * ELLW;
        float a0 = 0.f, a1 = 0.f, a2 = 0.f, a3 = 0.f, ax0 = 0.f, ax1 = 0.f;
#pragma unroll 4
        for (int jj = 0; jj < cn; ++jj) {
            const int m = cp[jj];
            const float v = vp[jj];
            const size_t mb = (size_t)m * 16 + b;
            const float4 g = *(const float4*)&t1h[mb * HH + qoff];
            a0 += v * g.x; a1 += v * g.y; a2 += v * g.z; a3 += v * g.w;
            if (w == 1) {
                const float2 gx = *(const float2*)&t1x[mb * 2];
                ax0 += v * gx.x; ax1 += v * gx.y;
            }
        }
        put(r, 2 + qoff + 0, hq.x);  put(r, 2 + qoff + 1, hq.y);
        put(r, 2 + qoff + 2, hq.z);  put(r, 2 + qoff + 3, hq.w);
        put(r, 68 + qoff + 0, tq.x); put(r, 68 + qoff + 1, tq.y);
        put(r, 68 + qoff + 2, tq.z); put(r, 68 + qoff + 3, tq.w);
        put(r, 134 + qoff + 0, 2.f * a0 - hq.x);
        put(r, 134 + qoff + 1, 2.f * a1 - hq.y);
        put(r, 134 + qoff + 2, 2.f * a2 - hq.z);
        put(r, 134 + qoff + 3, 2.f * a3 - hq.w);
        if (w == 1 && j == 0) {
            put(r, 0, xo0);   put(r, 1, xo1);
            put(r, 66, t160); put(r, 67, t161);
            put(r, 132, 2.f * ax0 - xo0);
            put(r, 133, 2.f * ax1 - xo1);
        }
    }
    __syncthreads();

    // ---- phase 2: MFMA GEMM (2 row-tiles x 4 gate-tiles)
    f32x4 acc[2][4];
#pragma unroll
    for (int rt = 0; rt < 2; ++rt)
#pragma unroll
        for (int g = 0; g < 4; ++g) acc[rt][g] = (f32x4){0.f, 0.f, 0.f, 0.f};

    for (int kc = 0; kc < 7; ++kc) {
        const int ko = kc * 32 + q * 8;
        bf16x8 ah[2], al[2];
#pragma unroll
        for (int rt = 0; rt < 2; ++rt) {
            ah[rt] = *(const bf16x8*)&Ah[rt * 16 + c16][ko];
            al[rt] = *(const bf16x8*)&Al[rt * 16 + c16][ko];
        }
        bf16x8 bh[4], bl[4];
#pragma unroll
        for (int g = 0; g < 4; ++g) {
            const int col = (w + 4 * g) * 16 + c16;
            const size_t wo = (size_t)col * KP + ko;
            bh[g] = *(const bf16x8*)(Wh + wo);
            bl[g] = *(const bf16x8*)(Wl + wo);
        }
#pragma unroll
        for (int rt = 0; rt < 2; ++rt)
#pragma unroll
            for (int g = 0; g < 4; ++g) {
                acc[rt][g] = __builtin_amdgcn_mfma_f32_16x16x32_bf16(ah[rt], bh[g], acc[rt][g], 0, 0, 0);
                acc[rt][g] = __builtin_amdgcn_mfma_f32_16x16x32_bf16(al[rt], bh[g], acc[rt][g], 0, 0, 0);
                acc[rt][g] = __builtin_amdgcn_mfma_f32_16x16x32_bf16(ah[rt], bl[g], acc[rt][g], 0, 0, 0);
            }
    }

    // ---- phase 3: LSTM elementwise (unit u = 16*w + c16 lane-local)
    const int u = 16 * w + c16;
    const float bi = bc[u], bfv = bc[64 + u], bo = bc[128 + u], bg = bc[192 + u];
    float h2v[2][4];
#pragma unroll
    for (int rt = 0; rt < 2; ++rt) {
        const int n = n0 + rt;
#pragma unroll
        for (int reg = 0; reg < 4; ++reg) {
            const int bb = q * 4 + reg;
            const size_t idx = ((size_t)n * 16 + bb) * HH + u;
            const float ig = sigmoidf_(acc[rt][0][reg] + bi);
            const float fg = sigmoidf_(acc[rt][1][reg] + bfv);
            const float og = sigmoidf_(acc[rt][2][reg] + bo);
            const float gg = tanhf_(acc[rt][3][reg] + bg);
            const float c2 = fg * c[idx] + ig * gg;
            const float h2 = og * tanhf_(c2);
            c[idx] = c2;
            h[idx] = h2;
            h2v[rt][reg] = h2;
        }
    }

    if (jslot >= 0) {
        const float w0u = W0[u * 2], w1u = W0[u * 2 + 1];
#pragma unroll
        for (int rt = 0; rt < 2; ++rt) {
#pragma unroll
            for (int reg = 0; reg < 4; ++reg) {
                float s0 = h2v[rt][reg] * w0u;
                float s1 = h2v[rt][reg] * w1u;
#pragma unroll
                for (int d = 1; d <= 8; d <<= 1) {
                    s0 += __shfl_xor(s0, d, 64);
                    s1 += __shfl_xor(s1, d, 64);
                }
                if (c16 == 0) {
                    const int lr = rt * 16 + q * 4 + reg;
                    proj[w][lr][0] = s0;
                    proj[w][lr][1] = s1;
                }
            }
        }
        __syncthreads();
        if (tid < 64) {
            const int lr = tid >> 1, comp = tid & 1;
            const float v = proj[0][lr][comp] + proj[1][lr][comp] +
                            proj[2][lr][comp] + proj[3][lr][comp] + b0[comp];
            const float y = tanhf_(v);
            const int n = n0 + (lr >> 4);
            const int bb = lr & 15;
            xout[((size_t)n * 16 + bb) * 2 + comp] = y;
            out[(((size_t)bb * FUT + jslot) * NN + n) * 2 + comp] = y;
        }
    }
}

// ---------------------------------------------------------------------------
extern "C" void kernel_launch(void* const* d_in, const int* in_sizes, int n_in,
                              void* d_out, int out_size, void* d_ws, size_t ws_size,
                              hipStream_t stream)
{
    const float* input = (const float*)d_in[0];   // [B,T,N,2]
    const float* L     = (const float*)d_in[1];   // [N,N]
    const float* W     = (const float*)d_in[2];   // [198,256]
    const float* bc    = (const float*)d_in[3];   // [256]
    const float* W0    = (const float*)d_in[4];   // [64,2]
    const float* b0    = (const float*)d_in[5];   // [2]

    char* ws = (char*)d_ws;
    size_t off = 0;
    auto carve = [&](size_t bytes) {
        void* p = ws + off;
        off += (bytes + 255) & ~(size_t)255;
        return p;
    };
    int*   cols  = (int*)  carve((size_t)NN * ELLW * 4);
    float* vals  = (float*)carve((size_t)NN * ELLW * 4);
    int*   cnt   = (int*)  carve((size_t)NN * 4);
    float* t1h   = (float*)carve((size_t)NN * 16 * HH * 4);
    float* t1x   = (float*)carve((size_t)NN * 16 * 2 * 4);
    float* h     = (float*)carve((size_t)NN * 16 * HH * 4);
    float* c     = (float*)carve((size_t)NN * 16 * HH * 4);
    float* xbuf  = (float*)carve((size_t)NN * 16 * 2 * 4);
    float* xtall = (float*)carve((size_t)TT * NN * 16 * 2 * 4);
    short* Wh    = (short*)carve((size_t)GG * KP * 2);
    short* Wl    = (short*)carve((size_t)GG * KP * 2);
    float* out   = (float*)d_out;

    build_ell<<<NN, 256, 0, stream>>>(L, cols, vals, cnt);
    wt_prep<<<GG, 256, 0, stream>>>(W, Wh, Wl);
    x_trans<<<(TT * NN * 16 * 2) / 256, 256, 0, stream>>>(input, xtall);
    hipMemsetAsync(h, 0, (size_t)NN * 16 * HH * 4, stream);
    hipMemsetAsync(c, 0, (size_t)NN * 16 * HH * 4, stream);

    for (int t = 0; t < TT; ++t) {
        const float* xt = xtall + (size_t)t * NN * 16 * 2;
        spmm_t1<<<NN, 256, 0, stream>>>(xt, h, cols, vals, cnt, t1h, t1x);
        cell_fused<<<NN / 2, 256, 0, stream>>>(xt, h, c, t1h, t1x, cols, vals, cnt,
                                               Wh, Wl, bc, W0, b0, xbuf, out,
                                               (t == TT - 1) ? 0 : -1);
    }
    for (int jstep = 1; jstep < FUT; ++jstep) {
        spmm_t1<<<NN, 256, 0, stream>>>(xbuf, h, cols, vals, cnt, t1h, t1x);
        cell_fused<<<NN / 2, 256, 0, stream>>>(xbuf, h, c, t1h, t1x, cols, vals, cnt,
                                               Wh, Wl, bc, W0, b0, xbuf, out, jstep);
    }
}